// Round 1
// 876.352 us; speedup vs baseline: 1.0256x; 1.0256x over previous
//
#include <hip/hip_runtime.h>
#include <math.h>

#define HD 128
#define FD 128
#define RD 64
#define TE 128          // edges per tile
#define RC_CUT 5.0f

typedef _Float16 half8_t __attribute__((ext_vector_type(8)));
typedef float floatx4 __attribute__((ext_vector_type(4)));

__device__ __forceinline__ float fast_tanh(float x) {
    float ex = __expf(2.0f * x);
    return 1.0f - 2.0f / (ex + 1.0f);
}

// ---------------- lin1: h = x @ lin1_w.T ----------------
__global__ __launch_bounds__(256) void lin1_kernel(const float* __restrict__ x,
                                                   const float* __restrict__ w,
                                                   float* __restrict__ h, int n)
{
    __shared__ float sx[16][HD];
    int base = blockIdx.x * 16;
    for (int i = threadIdx.x; i < 16 * HD; i += 256) {
        int r = i >> 7, c = i & 127;
        int row = base + r;
        sx[r][c] = (row < n) ? x[(size_t)row * HD + c] : 0.0f;
    }
    __syncthreads();
    int f = threadIdx.x & 127;
    int half = threadIdx.x >> 7;
    float acc[8];
#pragma unroll
    for (int r = 0; r < 8; ++r) acc[r] = 0.0f;
    const float* wrow = w + (size_t)f * HD;
    for (int k = 0; k < HD; ++k) {
        float wv = wrow[k];
#pragma unroll
        for (int r = 0; r < 8; ++r) acc[r] += sx[half * 8 + r][k] * wv;
    }
#pragma unroll
    for (int r = 0; r < 8; ++r) {
        int row = base + half * 8 + r;
        if (row < n) h[(size_t)row * FD + f] = acc[r];
    }
}

// ---------------- fused edge kernel (MFMA f16, 16 waves) ----------------
// LDS layout (dynamic, 80 KB):
//   sT  @ 0      : 32768 B  -- T tile (128 x 128 f16, row 256B, swizzled)
//                  (first 16384 B double as A tile 128 x 64 f16, row 128B)
//   sB1 @ 32768  : 16384 B  -- fw1 (128 x 64 f16, row 128B, swizzled)
//   sB2 @ 49152  : 32768 B  -- fw2 (128 x 128 f16, row 256B, swizzled)
// 1024 threads (16 waves): 80KB LDS -> 2 blocks/CU -> 32 waves/CU (100% occ),
// so one block's epilogue atomic/gather drain overlaps the other's GEMMs.
__device__ __forceinline__ half8_t lds_read8(const char* base, int row,
                                             int rowstride, int col) {
    int off = row * rowstride + ((col * 2) ^ ((row & 7) << 4));
    return *(const half8_t*)(base + off);
}

__global__ __launch_bounds__(1024, 8) void edge_kernel(
    const float* __restrict__ edge_weight,
    const float* __restrict__ edge_attr,
    const float* __restrict__ fw1, const float* __restrict__ fb1,
    const float* __restrict__ fw2, const float* __restrict__ fb2,
    const int* __restrict__ eidx,
    const float* __restrict__ h,
    float* agg, int E, int ntiles)
{
    extern __shared__ char smem[];
    char* sT  = smem;
    char* sB1 = smem + 32768;
    char* sB2 = smem + 49152;

    // ---- stage weights once per block (fp32 -> f16, swizzled) ----
    for (int i = threadIdx.x * 8; i < FD * RD; i += blockDim.x * 8) {
        int r = i >> 6, c = i & 63;
        const float4* g = (const float4*)(fw1 + (size_t)r * RD + c);
        float4 v0 = g[0], v1 = g[1];
        half8_t hv;
        hv[0] = (_Float16)v0.x; hv[1] = (_Float16)v0.y;
        hv[2] = (_Float16)v0.z; hv[3] = (_Float16)v0.w;
        hv[4] = (_Float16)v1.x; hv[5] = (_Float16)v1.y;
        hv[6] = (_Float16)v1.z; hv[7] = (_Float16)v1.w;
        *(half8_t*)(sB1 + r * 128 + ((c * 2) ^ ((r & 7) << 4))) = hv;
    }
    for (int i = threadIdx.x * 8; i < FD * FD; i += blockDim.x * 8) {
        int r = i >> 7, c = i & 127;
        const float4* g = (const float4*)(fw2 + (size_t)r * FD + c);
        float4 v0 = g[0], v1 = g[1];
        half8_t hv;
        hv[0] = (_Float16)v0.x; hv[1] = (_Float16)v0.y;
        hv[2] = (_Float16)v0.z; hv[3] = (_Float16)v0.w;
        hv[4] = (_Float16)v1.x; hv[5] = (_Float16)v1.y;
        hv[6] = (_Float16)v1.z; hv[7] = (_Float16)v1.w;
        *(half8_t*)(sB2 + r * 256 + ((c * 2) ^ ((r & 7) << 4))) = hv;
    }
    __syncthreads();

    const int* srcp = eidx;
    const int* dstp = eidx + E;
    int lane = threadIdx.x & 63;
    int wid  = threadIdx.x >> 6;   // 0..15
    int wm = wid >> 2;             // 0..3  (edge dim, 32 each)
    int wn = wid & 3;              // 0..3  (filter dim, 32 each)
    int l15 = lane & 15;
    int l4  = lane >> 4;

    for (int tile = blockIdx.x; tile < ntiles; tile += gridDim.x) {
        int e0 = tile * TE;
        // ---- stage A = edge_attr[e0:e0+128, :] as f16 into sT (row 128B) ----
        for (int i = threadIdx.x * 8; i < TE * RD; i += blockDim.x * 8) {
            int r = i >> 6, c = i & 63;
            half8_t hv;
            if (e0 + r < E) {
                const float4* g = (const float4*)(edge_attr + (size_t)(e0 + r) * RD + c);
                float4 v0 = g[0], v1 = g[1];
                hv[0] = (_Float16)v0.x; hv[1] = (_Float16)v0.y;
                hv[2] = (_Float16)v0.z; hv[3] = (_Float16)v0.w;
                hv[4] = (_Float16)v1.x; hv[5] = (_Float16)v1.y;
                hv[6] = (_Float16)v1.z; hv[7] = (_Float16)v1.w;
            } else {
                for (int q = 0; q < 8; ++q) hv[q] = (_Float16)0.0f;
            }
            *(half8_t*)(sT + r * 128 + ((c * 2) ^ ((r & 7) << 4))) = hv;
        }
        __syncthreads();

        // ---- GEMM1: C1 = A @ fw1^T   (128e x 128f, K=64) ----
        floatx4 acc[2][2];
#pragma unroll
        for (int mi = 0; mi < 2; ++mi)
#pragma unroll
            for (int ni = 0; ni < 2; ++ni)
                acc[mi][ni] = (floatx4){0.f, 0.f, 0.f, 0.f};
#pragma unroll
        for (int ks = 0; ks < 2; ++ks) {
            int k = ks * 32 + l4 * 8;
            half8_t a[2], b[2];
#pragma unroll
            for (int mi = 0; mi < 2; ++mi)
                a[mi] = lds_read8(sT, wm * 32 + mi * 16 + l15, 128, k);
#pragma unroll
            for (int ni = 0; ni < 2; ++ni)
                b[ni] = lds_read8(sB1, wn * 32 + ni * 16 + l15, 128, k);
#pragma unroll
            for (int mi = 0; mi < 2; ++mi)
#pragma unroll
                for (int ni = 0; ni < 2; ++ni)
                    acc[mi][ni] = __builtin_amdgcn_mfma_f32_16x16x32_f16(
                        a[mi], b[ni], acc[mi][ni], 0, 0, 0);
        }
        __syncthreads();   // A fully consumed; sT can be overwritten by T

        // ---- bias + tanh -> T (f16, row 256B, swizzled) ----
#pragma unroll
        for (int ni = 0; ni < 2; ++ni) {
            int f = wn * 32 + ni * 16 + l15;
            float bias = fb1[f];
#pragma unroll
            for (int mi = 0; mi < 2; ++mi) {
#pragma unroll
                for (int j = 0; j < 4; ++j) {
                    int e = wm * 32 + mi * 16 + l4 * 4 + j;
                    float t = fast_tanh(acc[mi][ni][j] + bias);
                    *(_Float16*)(sT + e * 256 + ((f * 2) ^ ((e & 7) << 4))) =
                        (_Float16)t;
                }
            }
        }
        __syncthreads();

        // ---- GEMM2: W = T @ fw2^T   (128e x 128g, K=128) ----
        floatx4 acc2[2][2];
#pragma unroll
        for (int mi = 0; mi < 2; ++mi)
#pragma unroll
            for (int ni = 0; ni < 2; ++ni)
                acc2[mi][ni] = (floatx4){0.f, 0.f, 0.f, 0.f};
#pragma unroll
        for (int ks = 0; ks < 4; ++ks) {
            int k = ks * 32 + l4 * 8;
            half8_t a[2], b[2];
#pragma unroll
            for (int mi = 0; mi < 2; ++mi)
                a[mi] = lds_read8(sT, wm * 32 + mi * 16 + l15, 256, k);
#pragma unroll
            for (int ni = 0; ni < 2; ++ni)
                b[ni] = lds_read8(sB2, wn * 32 + ni * 16 + l15, 256, k);
#pragma unroll
            for (int mi = 0; mi < 2; ++mi)
#pragma unroll
                for (int ni = 0; ni < 2; ++ni)
                    acc2[mi][ni] = __builtin_amdgcn_mfma_f32_16x16x32_f16(
                        a[mi], b[ni], acc2[mi][ni], 0, 0, 0);
        }
        __syncthreads();   // T consumed; next iter may overwrite sT

        // ---- epilogue: cutoff * h[src] gather, atomic scatter ----
        float bias2[2];
        int gcol[2];
#pragma unroll
        for (int ni = 0; ni < 2; ++ni) {
            gcol[ni] = wn * 32 + ni * 16 + l15;
            bias2[ni] = fb2[gcol[ni]];
        }
#pragma unroll
        for (int mi = 0; mi < 2; ++mi) {
            // batch the 4 edges' metadata loads ahead of the math
            int ge[4], s4[4], dn4[4];
            float d4[4];
#pragma unroll
            for (int j = 0; j < 4; ++j) {
                int el = wm * 32 + mi * 16 + l4 * 4 + j;
                ge[j] = e0 + el;
                int idx = (ge[j] < E) ? ge[j] : (E - 1);
                s4[j]  = srcp[idx];
                dn4[j] = dstp[idx];
                d4[j]  = edge_weight[idx];
            }
#pragma unroll
            for (int j = 0; j < 4; ++j) {
                if (ge[j] >= E) continue;
                float C = (d4[j] < RC_CUT)
                            ? 0.5f * (__cosf(d4[j] * 0.6283185307179586f) + 1.0f)
                            : 0.0f;
                const float* hrow = h + (size_t)s4[j] * FD;
                float* ar = agg + (size_t)dn4[j] * FD;
#pragma unroll
                for (int ni = 0; ni < 2; ++ni) {
                    int g = gcol[ni];
                    float wv = (acc2[mi][ni][j] + bias2[ni]) * C;
                    atomicAdd(ar + g, wv * hrow[g]);
                }
            }
        }
    }
}

// ---------------- final: disc conv + lin2 + tanh + lin ----------------
__global__ __launch_bounds__(256) void final_kernel(
    const float* aggin, const float* __restrict__ h,
    const float* __restrict__ disc_w,
    const float* __restrict__ lin2_w, const float* __restrict__ lin2_b,
    const float* __restrict__ lin_w, const float* __restrict__ lin_b,
    float* out, int n)
{
    __shared__ float sg[16][FD];
    __shared__ float sm[16][FD];
    int base = blockIdx.x * 16;
    for (int i = threadIdx.x; i < 16 * FD; i += 256) {
        int r = i >> 7, c = i & 127;
        int row = base + r;
        float v = 0.0f;
        if (row < n) {
            v = aggin[(size_t)row * FD + c] + disc_w[c] * h[(size_t)row * FD + c];
            if (row + 1 < n) v += disc_w[FD + c] * h[(size_t)(row + 1) * FD + c];
            if (row >= 1)    v += disc_w[2 * FD + c] * h[(size_t)(row - 1) * FD + c];
        }
        sg[r][c] = v;
    }
    __syncthreads();
    int f = threadIdx.x & 127;
    int half = threadIdx.x >> 7;
    {
        float acc[8];
        float b = lin2_b[f];
#pragma unroll
        for (int r = 0; r < 8; ++r) acc[r] = b;
        const float* wrow = lin2_w + (size_t)f * FD;
        for (int k = 0; k < FD; ++k) {
            float wv = wrow[k];
#pragma unroll
            for (int r = 0; r < 8; ++r) acc[r] += sg[half * 8 + r][k] * wv;
        }
#pragma unroll
        for (int r = 0; r < 8; ++r) sm[half * 8 + r][f] = fast_tanh(acc[r]);
    }
    __syncthreads();
    {
        float acc[8];
        float b = lin_b[f];
#pragma unroll
        for (int r = 0; r < 8; ++r) acc[r] = b;
        const float* wrow = lin_w + (size_t)f * HD;
        for (int k = 0; k < FD; ++k) {
            float wv = wrow[k];
#pragma unroll
            for (int r = 0; r < 8; ++r) acc[r] += sm[half * 8 + r][k] * wv;
        }
#pragma unroll
        for (int r = 0; r < 8; ++r) {
            int row = base + half * 8 + r;
            if (row < n) out[(size_t)row * HD + f] = acc[r];
        }
    }
}

extern "C" void kernel_launch(void* const* d_in, const int* in_sizes, int n_in,
                              void* d_out, int out_size, void* d_ws, size_t ws_size,
                              hipStream_t stream)
{
    const float* x      = (const float*)d_in[0];
    const float* ew     = (const float*)d_in[1];
    const float* ea     = (const float*)d_in[2];
    const float* fw1    = (const float*)d_in[3];
    const float* fb1    = (const float*)d_in[4];
    const float* fw2    = (const float*)d_in[5];
    const float* fb2    = (const float*)d_in[6];
    const float* lin1_w = (const float*)d_in[7];
    const float* lin2_w = (const float*)d_in[8];
    const float* lin2_b = (const float*)d_in[9];
    const float* disc_w = (const float*)d_in[10];
    const float* lin_w  = (const float*)d_in[11];
    const float* lin_b  = (const float*)d_in[12];
    const int*   eidx   = (const int*)d_in[13];

    int n = in_sizes[0] / HD;
    int E = in_sizes[1];
    float* out = (float*)d_out;
    float* h   = (float*)d_ws;   // (n,128) fp32

    hipMemsetAsync(d_out, 0, (size_t)out_size * sizeof(float), stream);

    lin1_kernel<<<(n + 15) / 16, 256, 0, stream>>>(x, lin1_w, h, n);

    int ntiles = (E + TE - 1) / TE;
    size_t smem = 81920;   // 80 KB -> 2 blocks/CU (2x1024 thr = 32 waves/CU)
    hipFuncSetAttribute((const void*)edge_kernel,
                        hipFuncAttributeMaxDynamicSharedMemorySize, (int)smem);
    int nblocks = ntiles < 512 ? ntiles : 512;   // 2/CU resident, grid-stride
    edge_kernel<<<nblocks, 1024, smem, stream>>>(ew, ea, fw1, fb1, fw2, fb2,
                                                 eidx, h, out, E, ntiles);

    final_kernel<<<(n + 15) / 16, 256, 0, stream>>>(out, h, disc_w, lin2_w, lin2_b,
                                                    lin_w, lin_b, out, n);
}